// Round 3
// baseline (360.751 us; speedup 1.0000x reference)
//
#include <hip/hip_runtime.h>

#define NN 50000
#define NE 800000
#define NEB 3125   // NE/256 edge blocks (1 edge/thread)
#define NHB 3125   // NN/16 projection blocks / node tiles
#define NTILES 3125
// inputs: node_features[NN*64] f32, edge_features[NE*32] f32, src[NE] i32,
//         dst[NE] i32, w_group[160] f32, w_srcattn[96] f32, w_lin[160*64] f32
// out: [NN*64] f32
//
// Algebra: a = ef·wg[0:32] + p1[src] + p2[dst]; t = p3[src]; u = ef·wa[64:96]
//          gamma = e^a / den_src[src]; s = t + gamma*u
// CSR by dst: cnt (fire-and-forget hist) -> off (prefix) -> cursor-atomic in
// k_edge claims pos and scatters the FULL 16B record {src,e,e^a,u}.
// (r1/r2 evidence: one 16B scattered write (~51MB dirty lines) beats the 4B-
// scatter + 2-random-gather alternative (+89MB fetch in k_reduce).)
// k_reduce gathers h rows as bf16 from hb (halves the dominant 205MB stream).
// hb[n][160] bf16 row = [bf16(h) | accum] is also the GEMM A-matrix.

typedef __attribute__((ext_vector_type(8))) short bf16x8;  // 8 bf16 (4 VGPRs)
typedef __attribute__((ext_vector_type(4))) short s16x4;
typedef __attribute__((ext_vector_type(4))) float f32x4;
typedef __attribute__((ext_vector_type(4))) int   i32x4;

static __device__ __forceinline__ short f2bf(float f) {
    unsigned int u = __float_as_uint(f);
    u += 0x7FFFu + ((u >> 16) & 1u);       // round-to-nearest-even
    return (short)(u >> 16);
}
static __device__ __forceinline__ float bf2f(short b) {
    return __uint_as_float(((unsigned)(unsigned short)b) << 16);
}

// ---------------------------------------------------------------------------
// Pass 0 (fused): blocks [0,NEB): dst histogram, fire-and-forget (no rank —
// CSR slot is claimed later by k_edge's cursor atomic).
// blocks [NEB,NEB+NHB): per-node projections (16 lanes/node, shfl reduce)
//   p1 = h·wg[32:96] ; pd = h·wg[96:160] ; dp[n].y = h·wa[0:64] (p3)
// plus bf16 copy of the h row into hb[n][0:64] (GEMM A + k_reduce gather).
// ---------------------------------------------------------------------------
__global__ __launch_bounds__(256) void k_pre(
    const float* __restrict__ h, const int* __restrict__ dst,
    const float* __restrict__ wg, const float* __restrict__ wa,
    int* __restrict__ cnt, float* __restrict__ p1, float* __restrict__ pd,
    float* __restrict__ dpf, short* __restrict__ hb)
{
    int tid = threadIdx.x;
    if (blockIdx.x < NEB) {
        int e = blockIdx.x * 256 + tid;
        if (e < NE) atomicAdd(&cnt[dst[e]], 1);   // no return -> no stall
        return;
    }
    __shared__ float4 ls[16], ld[16], lt[16];
    if (tid < 16)      ls[tid]      = ((const float4*)wg)[8 + tid];   // wg[32:96)
    else if (tid < 32) ld[tid - 16] = ((const float4*)wg)[8 + tid];   // wg[96:160)
    else if (tid < 48) lt[tid - 32] = ((const float4*)wa)[tid - 32];  // wa[0:64)
    __syncthreads();
    int n = (blockIdx.x - NEB) * 16 + (tid >> 4);
    if (n >= NN) return;
    int l16 = tid & 15;
    float4 v = ((const float4*)(h + (size_t)n * 64))[l16];
    s16x4 hv;
    hv[0] = f2bf(v.x); hv[1] = f2bf(v.y); hv[2] = f2bf(v.z); hv[3] = f2bf(v.w);
    *(s16x4*)(hb + (size_t)n * 160 + l16 * 4) = hv;
    float4 w1 = ls[l16], w2 = ld[l16], w3 = lt[l16];
    float s1 = v.x*w1.x + v.y*w1.y + v.z*w1.z + v.w*w1.w;
    float s2 = v.x*w2.x + v.y*w2.y + v.z*w2.z + v.w*w2.w;
    float s3 = v.x*w3.x + v.y*w3.y + v.z*w3.z + v.w*w3.w;
    #pragma unroll
    for (int m = 8; m; m >>= 1) {
        s1 += __shfl_xor(s1, m);
        s2 += __shfl_xor(s2, m);
        s3 += __shfl_xor(s3, m);
    }
    if (l16 == 0) { p1[n] = s1; pd[n] = s2; dpf[2 * n + 1] = s3; }
}

// ---------------------------------------------------------------------------
// Pass 1: contiguous (order-arbitrary) segment bases from cnt.
// Writes both off[n] (stable base, read by k_reduce) and cursor[n]
// (bumped by k_edge's slot-claim atomics; end-of-segment after k_edge).
// ---------------------------------------------------------------------------
__global__ __launch_bounds__(256) void k_assign(
    const int* __restrict__ cnt, int* __restrict__ off, int* __restrict__ cursor,
    int* __restrict__ gtotal)
{
    int n = blockIdx.x * 256 + threadIdx.x;
    int lane = threadIdx.x & 63;
    int c = (n < NN) ? cnt[n] : 0;
    int pre = c;
    #pragma unroll
    for (int d = 1; d < 64; d <<= 1) {
        int v = __shfl_up(pre, d);
        if (lane >= d) pre += v;
    }
    int base = 0;
    if (lane == 63) base = atomicAdd(gtotal, pre);
    base = __shfl(base, 63);
    if (n < NN) { int b = base + pre - c; off[n] = b; cursor[n] = b; }
}

// ---------------------------------------------------------------------------
// Pass 2: edge scoring, 1 edge/thread (r1: 2/thread halved occupancy, -19%).
// pos = atomicAdd(&cursor[d],1): claims the CSR slot (order-arbitrary within
// segment, which the reduce tolerates). Full 16B record scatter.
// den atomic is fire-and-forget.
// ---------------------------------------------------------------------------
__global__ __launch_bounds__(256) void k_edge(
    const float* __restrict__ ef, const int* __restrict__ src,
    const int* __restrict__ dst, const float* __restrict__ wg,
    const float* __restrict__ wa, const float* __restrict__ p1,
    const float* __restrict__ pd, float* __restrict__ dpf,
    int* __restrict__ cursor, i32x4* __restrict__ recA)
{
    __shared__ float4 lwe[8], lae[8];
    int tid = threadIdx.x;
    if (tid < 8)       lwe[tid]     = ((const float4*)wg)[tid];          // wg[0:32)
    else if (tid < 16) lae[tid - 8] = ((const float4*)wa)[tid - 8 + 16]; // wa[64:96)
    __syncthreads();
    int e = blockIdx.x * 256 + tid;
    if (e >= NE) return;
    int s = src[e], d = dst[e];
    float p1v = p1[s], pdv = pd[d];
    const float4* e4 = (const float4*)(ef + (size_t)e * 32);
    float a = 0.f, u = 0.f;
    #pragma unroll
    for (int q = 0; q < 8; ++q) {
        float4 v = e4[q], w = lwe[q], w2 = lae[q];
        a += v.x*w.x  + v.y*w.y  + v.z*w.z  + v.w*w.w;
        u += v.x*w2.x + v.y*w2.y + v.z*w2.z + v.w*w2.w;
    }
    float ev = __expf(a + p1v + pdv);
    atomicAdd(&dpf[2 * s], ev);            // den_src; no return needed
    int pos = atomicAdd(&cursor[d], 1);    // CSR slot claim
    recA[pos] = (i32x4){s, e, __float_as_int(ev), __float_as_int(u)};
}

// ---------------------------------------------------------------------------
// Pass 3: wave-per-node segmented softmax-reduce, 8-wide main loop.
// recA read sequentially (wave-uniform broadcast); h rows gathered as BF16
// from hb[src][0:64] -- 128B/row instead of 256B, halving the dominant
// gather stream. ef rows: lanes>=32 take the odd record of each pair; one
// shfl_xor(32) fold. bf16 accum store into hb[n][64:160].
// deg = cursor[n]-off[n] (cursor is end-of-segment after k_edge).
// ---------------------------------------------------------------------------
__global__ __launch_bounds__(256) void k_reduce(
    const float* __restrict__ ef, const int* __restrict__ off,
    const int* __restrict__ cursor, const float2* __restrict__ dp,
    const i32x4* __restrict__ recA, short* __restrict__ hb)
{
    int n = blockIdx.x * 4 + (threadIdx.x >> 6);
    if (n >= NN) return;
    int lane = threadIdx.x & 63;
    bool up = lane >= 32;
    int l5 = lane & 31;
    int base = off[n];
    int deg = cursor[n] - base;
    const i32x4* rp = recA + base;
    float acch = 0.f, acce = 0.f, den = 0.f;
    int j = 0;
    for (; j + 8 <= deg; j += 8) {
        i32x4 r[8];
        #pragma unroll
        for (int t = 0; t < 8; ++t) r[t] = rp[j + t];
        float2 dv[8]; float hv[8];
        #pragma unroll
        for (int t = 0; t < 8; ++t) {
            dv[t] = dp[r[t][0]];
            hv[t] = bf2f(hb[(size_t)(unsigned)r[t][0] * 160 + lane]);
        }
        float efv[4];
        #pragma unroll
        for (int t = 0; t < 4; ++t) {
            int ee = up ? r[2*t+1][1] : r[2*t][1];
            efv[t] = ef[((unsigned)ee << 5) + l5];
        }
        float g[8], s[8];
        #pragma unroll
        for (int t = 0; t < 8; ++t) {
            g[t] = __int_as_float(r[t][2]) * __builtin_amdgcn_rcpf(dv[t].x);
            s[t] = __expf(dv[t].y + g[t] * __int_as_float(r[t][3]));
            den  += s[t];
            acch += s[t] * hv[t];
        }
        #pragma unroll
        for (int t = 0; t < 4; ++t) {
            float w = up ? s[2*t+1]*g[2*t+1] : s[2*t]*g[2*t];
            acce += w * efv[t];
        }
    }
    if (j + 4 <= deg) {
        i32x4 r[4];
        #pragma unroll
        for (int t = 0; t < 4; ++t) r[t] = rp[j + t];
        float2 dv[4]; float hv[4];
        #pragma unroll
        for (int t = 0; t < 4; ++t) {
            dv[t] = dp[r[t][0]];
            hv[t] = bf2f(hb[(size_t)(unsigned)r[t][0] * 160 + lane]);
        }
        float efv[2];
        #pragma unroll
        for (int t = 0; t < 2; ++t) {
            int ee = up ? r[2*t+1][1] : r[2*t][1];
            efv[t] = ef[((unsigned)ee << 5) + l5];
        }
        float g[4], s[4];
        #pragma unroll
        for (int t = 0; t < 4; ++t) {
            g[t] = __int_as_float(r[t][2]) * __builtin_amdgcn_rcpf(dv[t].x);
            s[t] = __expf(dv[t].y + g[t] * __int_as_float(r[t][3]));
            den  += s[t];
            acch += s[t] * hv[t];
        }
        #pragma unroll
        for (int t = 0; t < 2; ++t) {
            float w = up ? s[2*t+1]*g[2*t+1] : s[2*t]*g[2*t];
            acce += w * efv[t];
        }
        j += 4;
    }
    for (; j < deg; ++j) {
        i32x4 r = rp[j];
        float2 dt = dp[r[0]];
        float g = __int_as_float(r[2]) * __builtin_amdgcn_rcpf(dt.x);
        float sx = __expf(dt.y + g * __int_as_float(r[3]));
        den += sx;
        acch += sx * bf2f(hb[(size_t)(unsigned)r[0] * 160 + lane]);
        if (!up) acce += sx * g * ef[((unsigned)r[1] << 5) + l5];
    }
    acce += __shfl_xor(acce, 32);          // fold odd-record (upper-lane) part
    float inv = (deg > 0) ? __builtin_amdgcn_rcpf(den) : 0.f;
    size_t hbase = (size_t)n * 160;
    hb[hbase + 64 + lane] = f2bf(acch * inv);
    if (!up) hb[hbase + 128 + l5] = f2bf(acce * inv);
}

// ---------------------------------------------------------------------------
// Pass 4: out = relu(hb @ w_lin) as an MFMA bf16 GEMM. A rows are already
// bf16 in hb[n][160] -> one 16B load per k-chunk. One 16-node tile per wave,
// 782 blocks (~3 waves/SIMD).
// Layouts (m89/m120-verified): A[m=lane&15][k=quad*8+j],
// B[k=quad*8+j][n=lane&15], D[row=quad*4+reg][col=lane&15].
// ---------------------------------------------------------------------------
__global__ __launch_bounds__(256) void k_node_update(
    const short* __restrict__ hb, const float* __restrict__ wl_g,
    float* __restrict__ out)
{
    int lane = threadIdx.x & 63;
    int col  = lane & 15;
    int quad = lane >> 4;
    int tile = blockIdx.x * 4 + (threadIdx.x >> 6);
    if (tile >= NTILES) return;

    bf16x8 bfr[5][4];
    #pragma unroll
    for (int kc = 0; kc < 5; ++kc)
        #pragma unroll
        for (int nt = 0; nt < 4; ++nt) {
            #pragma unroll
            for (int j = 0; j < 8; ++j) {
                int k = kc * 32 + quad * 8 + j;
                bfr[kc][nt][j] = f2bf(wl_g[k * 64 + nt * 16 + col]);
            }
        }

    int n = tile * 16 + col;                 // A-operand node (m = lane&15)
    f32x4 acc[4];
    #pragma unroll
    for (int nt = 0; nt < 4; ++nt) acc[nt] = (f32x4){0.f, 0.f, 0.f, 0.f};

    const short* hrow = hb + (size_t)n * 160 + quad * 8;
    #pragma unroll
    for (int kc = 0; kc < 5; ++kc) {
        bf16x8 af = *(const bf16x8*)(hrow + kc * 32);
        #pragma unroll
        for (int nt = 0; nt < 4; ++nt)
            acc[nt] = __builtin_amdgcn_mfma_f32_16x16x32_bf16(
                af, bfr[kc][nt], acc[nt], 0, 0, 0);
    }

    // D: row = quad*4 + r (node within tile), col = nt*16 + (lane&15)
    #pragma unroll
    for (int nt = 0; nt < 4; ++nt) {
        #pragma unroll
        for (int r = 0; r < 4; ++r) {
            int node = tile * 16 + quad * 4 + r;
            out[(size_t)node * 64 + nt * 16 + col] = fmaxf(acc[nt][r], 0.f);
        }
    }
}

// ---------------------------------------------------------------------------
// Workspace layout (4-byte words):
//   [0, 2NN)              dp     (float2 {den_src, p3}; zeroed)
//   [2NN, 3NN)            cnt    (int, zeroed)
//   [3NN, 3NN+16)         gtotal (int, zeroed)
//   [3NN+16, 4NN+16)      off    (int; stable CSR base)
//   [4NN+16, 5NN+16)      cursor (int; slot-claim, end-of-seg after k_edge)
//   [5NN+16, 6NN+16)      p1     (float)
//   [6NN+16, 7NN+16)      pd     (float)
//   [7NN+16, +4NE)        recA   (i32x4; byte off 1400064 %16==0)
//   [+4NE, +4NE+80NN)     hb     (bf16 [NN][160]; byte off 14200064 %16==0)
// total = 7NN+16 + 4NE + 80NN words = 7,550,016 words = 30.2 MB
// ---------------------------------------------------------------------------
extern "C" void kernel_launch(void* const* d_in, const int* in_sizes, int n_in,
                              void* d_out, int out_size, void* d_ws, size_t ws_size,
                              hipStream_t stream)
{
    const float* h   = (const float*)d_in[0];
    const float* ef  = (const float*)d_in[1];
    const int*   src = (const int*)d_in[2];
    const int*   dst = (const int*)d_in[3];
    const float* wg  = (const float*)d_in[4];
    const float* wa  = (const float*)d_in[5];
    const float* wl  = (const float*)d_in[6];
    float* out = (float*)d_out;

    float*  ws     = (float*)d_ws;
    float*  dpf    = ws;                       // float2 view at same addr
    int*    cnt    = (int*)(ws + 2 * NN);
    int*    gtotal = (int*)(ws + 3 * NN);
    int*    off    = (int*)(ws + 3 * NN + 16);
    int*    cursor = (int*)(ws + 4 * NN + 16);
    float*  p1     = ws + 5 * NN + 16;
    float*  pd     = ws + 6 * NN + 16;
    i32x4*  recA   = (i32x4*)(ws + 7 * NN + 16);
    short*  hb     = (short*)(ws + 7 * NN + 16 + 4 * NE);

    hipMemsetAsync(d_ws, 0, (size_t)(3 * NN + 16) * sizeof(float), stream);

    k_pre<<<NEB + NHB, 256, 0, stream>>>(h, dst, wg, wa, cnt, p1, pd, dpf, hb);
    k_assign<<<(NN + 255) / 256, 256, 0, stream>>>(cnt, off, cursor, gtotal);
    k_edge<<<NEB, 256, 0, stream>>>(ef, src, dst, wg, wa, p1, pd, dpf,
                                    cursor, recA);
    k_reduce<<<(NN + 3) / 4, 256, 0, stream>>>(ef, off, cursor,
                                               (const float2*)dpf, recA, hb);
    k_node_update<<<782, 256, 0, stream>>>(hb, wl, out);
}

// Round 4
// 339.874 us; speedup vs baseline: 1.0614x; 1.0614x over previous
//
#include <hip/hip_runtime.h>

#define NN 50000
#define NE 800000
#define NEB 3125   // NE/256 edge blocks (1 edge/thread)
#define NHB 3125   // NN/16 projection blocks / node tiles
#define NTILES 3125
// inputs: node_features[NN*64] f32, edge_features[NE*32] f32, src[NE] i32,
//         dst[NE] i32, w_group[160] f32, w_srcattn[96] f32, w_lin[160*64] f32
// out: [NN*64] f32
//
// Algebra: a = ef·wg[0:32] + p1[src] + p2[dst]; t = p3[src]; u = ef·wa[64:96]
//          gamma = e^a / den_src[src]; s = t + gamma*u
// CSR by dst: hist with rank (atomic-return hides in k_pre) -> off prefix ->
// k_edge scatters the FULL 16B record {src,e,e^a,u} at off[d]+rank[e] (pure
// loads, no atomic dependency -- r3's cursor-claim atomic cost +26us).
// k_reduce gathers h rows as bf16 from hb (2 lines -> 1 line per record).
// hb[n][160] bf16 row = [bf16(h) | accum] is also the GEMM A-matrix.
// wlbT[64][160] bf16 (transposed w_lin, built once) gives the GEMM B-frags
// as 16B vector loads instead of 160 scalar stride-256B loads per wave.

typedef __attribute__((ext_vector_type(8))) short bf16x8;  // 8 bf16 (4 VGPRs)
typedef __attribute__((ext_vector_type(4))) short s16x4;
typedef __attribute__((ext_vector_type(4))) float f32x4;
typedef __attribute__((ext_vector_type(4))) int   i32x4;

static __device__ __forceinline__ short f2bf(float f) {
    unsigned int u = __float_as_uint(f);
    u += 0x7FFFu + ((u >> 16) & 1u);       // round-to-nearest-even
    return (short)(u >> 16);
}
static __device__ __forceinline__ float bf2f(short b) {
    return __uint_as_float(((unsigned)(unsigned short)b) << 16);
}

// ---------------------------------------------------------------------------
// Pass 0 (fused): blocks [0,NEB): dst histogram + per-edge rank (the atomic
// return's only consumer is a coalesced 4B store -> latency hidden).
// blocks [NEB,NEB+NHB): per-node projections (16 lanes/node, shfl reduce)
//   p1 = h·wg[32:96] ; pd = h·wg[96:160] ; dp[n].y = h·wa[0:64] (p3)
// plus bf16 copy of the h row into hb[n][0:64] (GEMM A + k_reduce gather).
// ---------------------------------------------------------------------------
__global__ __launch_bounds__(256) void k_pre(
    const float* __restrict__ h, const int* __restrict__ dst,
    const float* __restrict__ wg, const float* __restrict__ wa,
    int* __restrict__ cnt, int* __restrict__ rank,
    float* __restrict__ p1, float* __restrict__ pd, float* __restrict__ dpf,
    short* __restrict__ hb)
{
    int tid = threadIdx.x;
    if (blockIdx.x < NEB) {
        int e = blockIdx.x * 256 + tid;
        if (e < NE) rank[e] = atomicAdd(&cnt[dst[e]], 1);
        return;
    }
    __shared__ float4 ls[16], ld[16], lt[16];
    if (tid < 16)      ls[tid]      = ((const float4*)wg)[8 + tid];   // wg[32:96)
    else if (tid < 32) ld[tid - 16] = ((const float4*)wg)[8 + tid];   // wg[96:160)
    else if (tid < 48) lt[tid - 32] = ((const float4*)wa)[tid - 32];  // wa[0:64)
    __syncthreads();
    int n = (blockIdx.x - NEB) * 16 + (tid >> 4);
    if (n >= NN) return;
    int l16 = tid & 15;
    float4 v = ((const float4*)(h + (size_t)n * 64))[l16];
    s16x4 hv;
    hv[0] = f2bf(v.x); hv[1] = f2bf(v.y); hv[2] = f2bf(v.z); hv[3] = f2bf(v.w);
    *(s16x4*)(hb + (size_t)n * 160 + l16 * 4) = hv;
    float4 w1 = ls[l16], w2 = ld[l16], w3 = lt[l16];
    float s1 = v.x*w1.x + v.y*w1.y + v.z*w1.z + v.w*w1.w;
    float s2 = v.x*w2.x + v.y*w2.y + v.z*w2.z + v.w*w2.w;
    float s3 = v.x*w3.x + v.y*w3.y + v.z*w3.z + v.w*w3.w;
    #pragma unroll
    for (int m = 8; m; m >>= 1) {
        s1 += __shfl_xor(s1, m);
        s2 += __shfl_xor(s2, m);
        s3 += __shfl_xor(s3, m);
    }
    if (l16 == 0) { p1[n] = s1; pd[n] = s2; dpf[2 * n + 1] = s3; }
}

// ---------------------------------------------------------------------------
// Pass 1: blocks [0,196): contiguous (order-arbitrary) segment bases from cnt.
// blocks [196,236): one-time w_lin -> wlbT bf16 transpose (10240 elements;
// read coalesced, 20KB scatter write merges in L2).
// ---------------------------------------------------------------------------
__global__ __launch_bounds__(256) void k_assign(
    const int* __restrict__ cnt, int* __restrict__ off, int* __restrict__ gtotal,
    const float* __restrict__ wl, short* __restrict__ wlbT)
{
    if (blockIdx.x >= 196) {
        int idx = (blockIdx.x - 196) * 256 + threadIdx.x;   // [0,10240)
        int k = idx >> 6, nn = idx & 63;
        wlbT[nn * 160 + k] = f2bf(wl[idx]);
        return;
    }
    int n = blockIdx.x * 256 + threadIdx.x;
    int lane = threadIdx.x & 63;
    int c = (n < NN) ? cnt[n] : 0;
    int pre = c;
    #pragma unroll
    for (int d = 1; d < 64; d <<= 1) {
        int v = __shfl_up(pre, d);
        if (lane >= d) pre += v;
    }
    int base = 0;
    if (lane == 63) base = atomicAdd(gtotal, pre);
    base = __shfl(base, 63);
    if (n < NN) off[n] = base + pre - c;
}

// ---------------------------------------------------------------------------
// Pass 2: edge scoring, 1 edge/thread. pos = off[d]+rank[e] (pure loads, no
// atomic dependency). Full 16B record scatter. den atomic fire-and-forget.
// ---------------------------------------------------------------------------
__global__ __launch_bounds__(256) void k_edge(
    const float* __restrict__ ef, const int* __restrict__ src,
    const int* __restrict__ dst, const int* __restrict__ rank,
    const float* __restrict__ wg, const float* __restrict__ wa,
    const float* __restrict__ p1, const float* __restrict__ pd,
    float* __restrict__ dpf, const int* __restrict__ off,
    i32x4* __restrict__ recA)
{
    __shared__ float4 lwe[8], lae[8];
    int tid = threadIdx.x;
    if (tid < 8)       lwe[tid]     = ((const float4*)wg)[tid];          // wg[0:32)
    else if (tid < 16) lae[tid - 8] = ((const float4*)wa)[tid - 8 + 16]; // wa[64:96)
    __syncthreads();
    int e = blockIdx.x * 256 + tid;
    if (e >= NE) return;
    int s = src[e], d = dst[e], rk = rank[e];
    float p1v = p1[s], pdv = pd[d];
    int pos = off[d] + rk;
    const float4* e4 = (const float4*)(ef + (size_t)e * 32);
    float a = 0.f, u = 0.f;
    #pragma unroll
    for (int q = 0; q < 8; ++q) {
        float4 v = e4[q], w = lwe[q], w2 = lae[q];
        a += v.x*w.x  + v.y*w.y  + v.z*w.z  + v.w*w.w;
        u += v.x*w2.x + v.y*w2.y + v.z*w2.z + v.w*w2.w;
    }
    float ev = __expf(a + p1v + pdv);
    atomicAdd(&dpf[2 * s], ev);            // den_src; no return needed
    recA[pos] = (i32x4){s, e, __float_as_int(ev), __float_as_int(u)};
}

// ---------------------------------------------------------------------------
// Pass 3: wave-per-node segmented softmax-reduce, 8-wide main loop.
// recA read sequentially (wave-uniform); h rows gathered as BF16 from
// hb[src][0:64] (1 line per half-row instead of 2 for f32). ef rows:
// lanes>=32 take the odd record of each pair; one shfl_xor(32) fold.
// bf16 accum store into hb[n][64:160].
// ---------------------------------------------------------------------------
__global__ __launch_bounds__(256) void k_reduce(
    const float* __restrict__ ef, const int* __restrict__ cnt,
    const int* __restrict__ off, const float2* __restrict__ dp,
    const i32x4* __restrict__ recA, short* __restrict__ hb)
{
    int n = blockIdx.x * 4 + (threadIdx.x >> 6);
    if (n >= NN) return;
    int lane = threadIdx.x & 63;
    bool up = lane >= 32;
    int l5 = lane & 31;
    int deg = cnt[n], base = off[n];
    const i32x4* rp = recA + base;
    float acch = 0.f, acce = 0.f, den = 0.f;
    int j = 0;
    for (; j + 8 <= deg; j += 8) {
        i32x4 r[8];
        #pragma unroll
        for (int t = 0; t < 8; ++t) r[t] = rp[j + t];
        float2 dv[8]; float hv[8];
        #pragma unroll
        for (int t = 0; t < 8; ++t) {
            dv[t] = dp[r[t][0]];
            hv[t] = bf2f(hb[(size_t)(unsigned)r[t][0] * 160 + lane]);
        }
        float efv[4];
        #pragma unroll
        for (int t = 0; t < 4; ++t) {
            int ee = up ? r[2*t+1][1] : r[2*t][1];
            efv[t] = ef[((unsigned)ee << 5) + l5];
        }
        float g[8], s[8];
        #pragma unroll
        for (int t = 0; t < 8; ++t) {
            g[t] = __int_as_float(r[t][2]) * __builtin_amdgcn_rcpf(dv[t].x);
            s[t] = __expf(dv[t].y + g[t] * __int_as_float(r[t][3]));
            den  += s[t];
            acch += s[t] * hv[t];
        }
        #pragma unroll
        for (int t = 0; t < 4; ++t) {
            float w = up ? s[2*t+1]*g[2*t+1] : s[2*t]*g[2*t];
            acce += w * efv[t];
        }
    }
    if (j + 4 <= deg) {
        i32x4 r[4];
        #pragma unroll
        for (int t = 0; t < 4; ++t) r[t] = rp[j + t];
        float2 dv[4]; float hv[4];
        #pragma unroll
        for (int t = 0; t < 4; ++t) {
            dv[t] = dp[r[t][0]];
            hv[t] = bf2f(hb[(size_t)(unsigned)r[t][0] * 160 + lane]);
        }
        float efv[2];
        #pragma unroll
        for (int t = 0; t < 2; ++t) {
            int ee = up ? r[2*t+1][1] : r[2*t][1];
            efv[t] = ef[((unsigned)ee << 5) + l5];
        }
        float g[4], s[4];
        #pragma unroll
        for (int t = 0; t < 4; ++t) {
            g[t] = __int_as_float(r[t][2]) * __builtin_amdgcn_rcpf(dv[t].x);
            s[t] = __expf(dv[t].y + g[t] * __int_as_float(r[t][3]));
            den  += s[t];
            acch += s[t] * hv[t];
        }
        #pragma unroll
        for (int t = 0; t < 2; ++t) {
            float w = up ? s[2*t+1]*g[2*t+1] : s[2*t]*g[2*t];
            acce += w * efv[t];
        }
        j += 4;
    }
    for (; j < deg; ++j) {
        i32x4 r = rp[j];
        float2 dt = dp[r[0]];
        float g = __int_as_float(r[2]) * __builtin_amdgcn_rcpf(dt.x);
        float sx = __expf(dt.y + g * __int_as_float(r[3]));
        den += sx;
        acch += sx * bf2f(hb[(size_t)(unsigned)r[0] * 160 + lane]);
        if (!up) acce += sx * g * ef[((unsigned)r[1] << 5) + l5];
    }
    acce += __shfl_xor(acce, 32);          // fold odd-record (upper-lane) part
    float inv = (deg > 0) ? __builtin_amdgcn_rcpf(den) : 0.f;
    size_t hbase = (size_t)n * 160;
    hb[hbase + 64 + lane] = f2bf(acch * inv);
    if (!up) hb[hbase + 128 + l5] = f2bf(acce * inv);
}

// ---------------------------------------------------------------------------
// Pass 4: out = relu(hb @ w_lin) as an MFMA bf16 GEMM. A rows are bf16 in
// hb[n][160]; B-frags are 16B vector loads from wlbT[64][160] (transposed
// bf16 w_lin) -- was 160 scalar stride-256B f32 loads + f2bf per wave.
// Grid 391 blocks (1564 waves, 2 tiles/wave): B-frags amortized over 2 tiles.
// Layouts (m89/m120-verified): A[m=lane&15][k=quad*8+j],
// B[k=quad*8+j][n=lane&15], D[row=quad*4+reg][col=lane&15].
// ---------------------------------------------------------------------------
__global__ __launch_bounds__(256) void k_node_update(
    const short* __restrict__ hb, const short* __restrict__ wlbT,
    float* __restrict__ out)
{
    int lane = threadIdx.x & 63;
    int col  = lane & 15;
    int quad = lane >> 4;
    int wid  = blockIdx.x * 4 + (threadIdx.x >> 6);
    int nwaves = gridDim.x * 4;

    bf16x8 bfr[5][4];
    #pragma unroll
    for (int nt = 0; nt < 4; ++nt) {
        const short* bp = wlbT + (size_t)(nt * 16 + col) * 160 + quad * 8;
        #pragma unroll
        for (int kc = 0; kc < 5; ++kc)
            bfr[kc][nt] = *(const bf16x8*)(bp + kc * 32);
    }

    for (int tile = wid; tile < NTILES; tile += nwaves) {
        int n = tile * 16 + col;             // A-operand node (m = lane&15)
        f32x4 acc[4];
        #pragma unroll
        for (int nt = 0; nt < 4; ++nt) acc[nt] = (f32x4){0.f, 0.f, 0.f, 0.f};

        const short* hrow = hb + (size_t)n * 160 + quad * 8;
        #pragma unroll
        for (int kc = 0; kc < 5; ++kc) {
            bf16x8 af = *(const bf16x8*)(hrow + kc * 32);
            #pragma unroll
            for (int nt = 0; nt < 4; ++nt)
                acc[nt] = __builtin_amdgcn_mfma_f32_16x16x32_bf16(
                    af, bfr[kc][nt], acc[nt], 0, 0, 0);
        }

        // D: row = quad*4 + r (node within tile), col = nt*16 + (lane&15)
        #pragma unroll
        for (int nt = 0; nt < 4; ++nt) {
            #pragma unroll
            for (int r = 0; r < 4; ++r) {
                int node = tile * 16 + quad * 4 + r;
                out[(size_t)node * 64 + nt * 16 + col] = fmaxf(acc[nt][r], 0.f);
            }
        }
    }
}

// ---------------------------------------------------------------------------
// Workspace layout (4-byte words):
//   [0, 2NN)              dp     (float2 {den_src, p3}; zeroed)
//   [2NN, 3NN)            cnt    (int, zeroed)
//   [3NN, 3NN+16)         gtotal (int, zeroed)
//   [3NN+16, 4NN+16)      off    (int)
//   [4NN+16, 5NN+16)      p1     (float)
//   [5NN+16, 6NN+16)      pd     (float)
//   [6NN+16, +NE)         rank   (int)
//   [+NE, +NE+5120)       wlbT   (bf16 [64][160]; byte off 4400064 %16==0)
//   [+NE+5120, +5NE+5120) recA   (i32x4; byte off 4420544 %16==0)
//   [..., +80NN]          hb     (bf16 [NN][160]; byte off 17220544 %16==0)
// total = 6NN+16 + 5NE + 5120 + 80NN words = 8,305,136 words ≈ 33.2 MB
// ---------------------------------------------------------------------------
extern "C" void kernel_launch(void* const* d_in, const int* in_sizes, int n_in,
                              void* d_out, int out_size, void* d_ws, size_t ws_size,
                              hipStream_t stream)
{
    const float* h   = (const float*)d_in[0];
    const float* ef  = (const float*)d_in[1];
    const int*   src = (const int*)d_in[2];
    const int*   dst = (const int*)d_in[3];
    const float* wg  = (const float*)d_in[4];
    const float* wa  = (const float*)d_in[5];
    const float* wl  = (const float*)d_in[6];
    float* out = (float*)d_out;

    float*  ws     = (float*)d_ws;
    float*  dpf    = ws;                       // float2 view at same addr
    int*    cnt    = (int*)(ws + 2 * NN);
    int*    gtotal = (int*)(ws + 3 * NN);
    int*    off    = (int*)(ws + 3 * NN + 16);
    float*  p1     = ws + 4 * NN + 16;
    float*  pd     = ws + 5 * NN + 16;
    int*    rank   = (int*)(ws + 6 * NN + 16);
    short*  wlbT   = (short*)(ws + 6 * NN + 16 + NE);
    i32x4*  recA   = (i32x4*)(ws + 6 * NN + 16 + NE + 5120);
    short*  hb     = (short*)(ws + 6 * NN + 16 + 5 * NE + 5120);

    hipMemsetAsync(d_ws, 0, (size_t)(3 * NN + 16) * sizeof(float), stream);

    k_pre<<<NEB + NHB, 256, 0, stream>>>(h, dst, wg, wa, cnt, rank, p1, pd,
                                         dpf, hb);
    k_assign<<<236, 256, 0, stream>>>(cnt, off, gtotal, wl, wlbT);
    k_edge<<<NEB, 256, 0, stream>>>(ef, src, dst, rank, wg, wa, p1, pd, dpf,
                                    off, recA);
    k_reduce<<<(NN + 3) / 4, 256, 0, stream>>>(ef, cnt, off,
                                               (const float2*)dpf, recA, hb);
    k_node_update<<<391, 256, 0, stream>>>(hb, wlbT, out);
}